// Round 2
// baseline (679.642 us; speedup 1.0000x reference)
//
#include <hip/hip_runtime.h>
#include <hip/hip_bf16.h>

// Problem: B=64, L=4096, D=512, fp32.
// context[b,d] = (1/L) * sum_l softmax_l(energy[b,:]) * enc[b,l,d],
// energy[b,l] = dot(h[b,:], enc[b,l,:]).
//
// Single fused pass over enc (512 MiB => ~85us HBM floor). Online softmax.
// R1 change: each wave keeps TWO independent online-softmax states (even/odd
// rows) => 2x memory-level parallelism (4 KiB in flight/wave) and 2x ILP on
// the dependent shuffle-reduce chains. States merged per-wave, then per-block
// in LDS, then a tiny pass2 merges chunks.

#define D_DIM 512
#define B_DIM 64
#define L_DIM 4096

__device__ __forceinline__ float dot8(const float4& ha, const float4& hb,
                                      const float4& va, const float4& vb) {
    return ha.x * va.x + ha.y * va.y + ha.z * va.z + ha.w * va.w
         + hb.x * vb.x + hb.y * vb.y + hb.z * vb.z + hb.w * vb.w;
}

__global__ __launch_bounds__(256) void attn_pass1(
    const float* __restrict__ h,      // [B, D]
    const float* __restrict__ enc,    // [B, L, D]
    float* __restrict__ part_ms,      // [B, C, 2]  (m, s)
    float* __restrict__ part_ctx,     // [B, C, D]
    int Cblk)
{
    const int b    = blockIdx.y;
    const int c    = blockIdx.x;
    const int tid  = threadIdx.x;
    const int wave = tid >> 6;
    const int lane = tid & 63;

    const int rowsPerBlock = L_DIM / Cblk;       // 256 at C=16
    const int rowsPerWave  = rowsPerBlock >> 2;  // 64
    const int pairs        = rowsPerWave >> 1;   // 32
    const int l0 = c * rowsPerBlock + wave * rowsPerWave;

    // h fragment: lane covers d = 4*lane..+3 and 256+4*lane..+3
    const float4* h4 = reinterpret_cast<const float4*>(h + (size_t)b * D_DIM);
    const float4 h0 = h4[lane];
    const float4 h1 = h4[lane + 64];

    const float* p0 = enc + ((size_t)b * L_DIM + (size_t)l0) * D_DIM + 4 * lane;
    const float* p1 = p0 + D_DIM;

    // Two independent online-softmax states (even rows / odd rows).
    float  m0 = -3.0e38f, s0 = 0.0f;
    float  m1 = -3.0e38f, s1 = 0.0f;
    float4 a00 = {0,0,0,0}, a01 = {0,0,0,0};   // state0: d-lo, d-hi
    float4 a10 = {0,0,0,0}, a11 = {0,0,0,0};   // state1

    float4 v00 = *reinterpret_cast<const float4*>(p0);
    float4 v01 = *reinterpret_cast<const float4*>(p0 + 256);
    float4 v10 = *reinterpret_cast<const float4*>(p1);
    float4 v11 = *reinterpret_cast<const float4*>(p1 + 256);

    for (int r = 0; r < pairs; ++r) {
        // prefetch next pair (clamped on last iter -> L1 hit, values unused)
        const int adv = (r + 1 < pairs) ? 2 * D_DIM : 0;
        const float* n0 = p0 + adv;
        const float* n1 = p1 + adv;
        const float4 nv00 = *reinterpret_cast<const float4*>(n0);
        const float4 nv01 = *reinterpret_cast<const float4*>(n0 + 256);
        const float4 nv10 = *reinterpret_cast<const float4*>(n1);
        const float4 nv11 = *reinterpret_cast<const float4*>(n1 + 256);

        float e0 = dot8(h0, h1, v00, v01);
        float e1 = dot8(h0, h1, v10, v11);
        // two independent 64-lane reductions, interleaved for ILP
        #pragma unroll
        for (int off = 32; off > 0; off >>= 1) {
            e0 += __shfl_xor(e0, off, 64);
            e1 += __shfl_xor(e1, off, 64);
        }

        // state0 update (wave-uniform branch, taken ~log(rows) times)
        if (e0 > m0) {
            const float al = __expf(m0 - e0);
            s0 *= al;
            a00.x *= al; a00.y *= al; a00.z *= al; a00.w *= al;
            a01.x *= al; a01.y *= al; a01.z *= al; a01.w *= al;
            m0 = e0;
        }
        const float w0 = __expf(e0 - m0);
        s0 += w0;
        a00.x += w0 * v00.x; a00.y += w0 * v00.y; a00.z += w0 * v00.z; a00.w += w0 * v00.w;
        a01.x += w0 * v01.x; a01.y += w0 * v01.y; a01.z += w0 * v01.z; a01.w += w0 * v01.w;

        // state1 update
        if (e1 > m1) {
            const float al = __expf(m1 - e1);
            s1 *= al;
            a10.x *= al; a10.y *= al; a10.z *= al; a10.w *= al;
            a11.x *= al; a11.y *= al; a11.z *= al; a11.w *= al;
            m1 = e1;
        }
        const float w1 = __expf(e1 - m1);
        s1 += w1;
        a10.x += w1 * v10.x; a10.y += w1 * v10.y; a10.z += w1 * v10.z; a10.w += w1 * v10.w;
        a11.x += w1 * v11.x; a11.y += w1 * v11.y; a11.z += w1 * v11.z; a11.w += w1 * v11.w;

        v00 = nv00; v01 = nv01; v10 = nv10; v11 = nv11;
        p0 += 2 * D_DIM; p1 += 2 * D_DIM;
    }

    // merge state1 into state0 (per-wave)
    {
        const float M  = fmaxf(m0, m1);
        const float w0 = __expf(m0 - M);
        const float w1 = __expf(m1 - M);
        s0 = s0 * w0 + s1 * w1;
        a00.x = a00.x * w0 + a10.x * w1; a00.y = a00.y * w0 + a10.y * w1;
        a00.z = a00.z * w0 + a10.z * w1; a00.w = a00.w * w0 + a10.w * w1;
        a01.x = a01.x * w0 + a11.x * w1; a01.y = a01.y * w0 + a11.y * w1;
        a01.z = a01.z * w0 + a11.z * w1; a01.w = a01.w * w0 + a11.w * w1;
        m0 = M;
    }

    // ---- combine the 4 waves of this block in LDS ----
    __shared__ float sm_m[4];
    __shared__ float sm_s[4];
    __shared__ float sm_ctx[4][D_DIM];

    reinterpret_cast<float4*>(&sm_ctx[wave][0])[lane]   = a00;
    reinterpret_cast<float4*>(&sm_ctx[wave][256])[lane] = a01;
    if (lane == 0) { sm_m[wave] = m0; sm_s[wave] = s0; }
    __syncthreads();

    const float M  = fmaxf(fmaxf(sm_m[0], sm_m[1]), fmaxf(sm_m[2], sm_m[3]));
    const float w0 = __expf(sm_m[0] - M);
    const float w1 = __expf(sm_m[1] - M);
    const float w2 = __expf(sm_m[2] - M);
    const float w3 = __expf(sm_m[3] - M);

    if (tid == 0) {
        const float S = sm_s[0] * w0 + sm_s[1] * w1 + sm_s[2] * w2 + sm_s[3] * w3;
        float* ms = part_ms + ((size_t)b * Cblk + c) * 2;
        ms[0] = M;
        ms[1] = S;
    }

    float* dst = part_ctx + ((size_t)b * Cblk + c) * D_DIM;
    for (int d = tid; d < D_DIM; d += 256) {
        dst[d] = sm_ctx[0][d] * w0 + sm_ctx[1][d] * w1
               + sm_ctx[2][d] * w2 + sm_ctx[3][d] * w3;
    }
}

__global__ __launch_bounds__(256) void attn_pass2(
    const float* __restrict__ part_ms,   // [B, C, 2]
    const float* __restrict__ part_ctx,  // [B, C, D]
    float* __restrict__ out,             // [B, D]
    int Cblk, float invL)
{
    const int b   = blockIdx.x;
    const int tid = threadIdx.x;

    __shared__ float w_sm[64];
    __shared__ float invSL;

    if (tid == 0) {
        const float* ms = part_ms + (size_t)b * Cblk * 2;
        float M = -3.0e38f;
        for (int i = 0; i < Cblk; ++i) M = fmaxf(M, ms[2 * i]);
        float S = 0.f;
        for (int i = 0; i < Cblk; ++i) {
            const float w = __expf(ms[2 * i] - M);
            w_sm[i] = w;
            S += w * ms[2 * i + 1];
        }
        invSL = invL / S;
    }
    __syncthreads();

    const float scale = invSL;
    for (int d = tid; d < D_DIM; d += 256) {
        float acc = 0.f;
        for (int i = 0; i < Cblk; ++i)
            acc += w_sm[i] * part_ctx[((size_t)b * Cblk + i) * D_DIM + d];
        out[(size_t)b * D_DIM + d] = acc * scale;
    }
}

extern "C" void kernel_launch(void* const* d_in, const int* in_sizes, int n_in,
                              void* d_out, int out_size, void* d_ws, size_t ws_size,
                              hipStream_t stream) {
    const float* h   = (const float*)d_in[0];  // [B, D]
    const float* enc = (const float*)d_in[1];  // [B, L, D]
    float* out = (float*)d_out;                // [B, D]

    // 16 chunks/batch -> 1024 blocks -> 4 blocks/CU (16 waves/CU).
    int C = 16;
    while (C > 1) {
        const size_t need = ((size_t)B_DIM * C * 2 + (size_t)B_DIM * C * D_DIM) * sizeof(float);
        if (need <= ws_size) break;
        C >>= 1;
    }

    float* part_ms  = (float*)d_ws;
    float* part_ctx = part_ms + (size_t)B_DIM * C * 2;  // 16B-aligned

    dim3 grid1(C, B_DIM);
    attn_pass1<<<grid1, 256, 0, stream>>>(h, enc, part_ms, part_ctx, C);
    attn_pass2<<<B_DIM, 256, 0, stream>>>(part_ms, part_ctx, out, C, 1.0f / (float)L_DIM);
}